// Round 3
// baseline (1209.606 us; speedup 1.0000x reference)
//
#include <hip/hip_runtime.h>
#include <math.h>

#define NN 200000      // nodes
#define NE 6400000     // edges
#define FIN 100        // input feature dim
#define MR 10000       // sampled rows (NN/20)
#define SCAN_NB 196    // ceil(NN/1024)
#define NPASS 8        // fallback scatter passes
#define PRANGE 25000   // NN / NPASS
#define BSH 14         // coarse bucket shift (16384-node windows)
#define NBK 13         // ceil(NN / 16384)
#define EPB 4096       // edges per block in k_bucket

// ---------- float <-> monotonic-uint encoding for atomic min/max ----------
static __device__ __forceinline__ unsigned enc_f(float f){
  unsigned u = __float_as_uint(f);
  return (u & 0x80000000u) ? ~u : (u | 0x80000000u);
}
static __device__ __forceinline__ float dec_f(unsigned u){
  return (u & 0x80000000u) ? __uint_as_float(u ^ 0x80000000u) : __uint_as_float(~u);
}
// ---------- fp32 <-> bf16 (round-nearest-even) ----------
static __device__ __forceinline__ unsigned short f2bf(float f){
  unsigned u = __float_as_uint(f);
  return (unsigned short)((u + 0x7fffu + ((u >> 16) & 1u)) >> 16);
}
static __device__ __forceinline__ float bf2f(unsigned short h){
  return __uint_as_float(((unsigned)h) << 16);
}

// ---------- init: deg=1 (self loop), offs[NN]=NE, minmax identity, bcnt=0 ----------
__global__ void k_init(int* deg, int* offs, unsigned* mm, int* bcnt){
  int i = blockIdx.x*blockDim.x + threadIdx.x;
  if(i < NN) deg[i] = 1;
  if(i < NBK) bcnt[i] = 0;
  if(i == 0){ offs[NN] = NE; mm[0] = 0xFFFFFFFFu; mm[1] = 0u; }
}

// ---------- coarse bucket histogram over dst ----------
__global__ __launch_bounds__(256) void k_bhist(const int4* __restrict__ dst4,
                                               int* __restrict__ bcnt){
  __shared__ int sh[16];
  int t = threadIdx.x;
  if(t < 16) sh[t] = 0;
  __syncthreads();
  int q = blockIdx.x*256 + t;          // q < NE/4 (exact)
  int4 d = dst4[q];
  atomicAdd(&sh[d.x>>BSH], 1);
  atomicAdd(&sh[d.y>>BSH], 1);
  atomicAdd(&sh[d.z>>BSH], 1);
  atomicAdd(&sh[d.w>>BSH], 1);
  __syncthreads();
  if(t < NBK && sh[t]) atomicAdd(&bcnt[t], sh[t]);
}

__global__ void k_bscan(const int* __restrict__ bcnt, int* bbase, int* bcur){
  if(threadIdx.x == 0 && blockIdx.x == 0){
    int run = 0;
    for(int b=0;b<NBK;b++){ bbase[b] = run; bcur[b] = run; run += bcnt[b]; }
  }
}

// ---------- phase A: bucketize edges by dst>>BSH + fold in deg histogram ----------
// LDS-staged partition: per-block bucket counts via LDS atomics, one global
// reserve atomic per bucket per block, coalesced segment copy-out.
__global__ __launch_bounds__(256) void k_bucket(const int* __restrict__ src,
                                                const int* __restrict__ dst,
                                                int* __restrict__ deg,
                                                int* __restrict__ bcur,
                                                int* __restrict__ bsrc,
                                                unsigned short* __restrict__ bdst){
  __shared__ int cnt[NBK], bst[NBK], gbase[NBK];
  __shared__ int2 stage[EPB];
  int t = threadIdx.x;
  long ebase = (long)blockIdx.x * EPB;
  int nEdge = (int)min((long)EPB, (long)NE - ebase);
  if(t < NBK) cnt[t] = 0;
  __syncthreads();
  int ex[16], ey[16], rr[16];
  const int4* s4 = (const int4*)(src + ebase);
  const int4* d4 = (const int4*)(dst + ebase);
  #pragma unroll
  for(int j=0;j<4;j++){
    int q  = t + j*256;      // int4 index within block
    int eo = q*4;            // edge offset within block
    if(eo < nEdge){
      int4 s = s4[q]; int4 d = d4[q];
      ex[j*4+0]=s.x; ey[j*4+0]=d.x;
      ex[j*4+1]=s.y; ey[j*4+1]=d.y;
      ex[j*4+2]=s.z; ey[j*4+2]=d.z;
      ex[j*4+3]=s.w; ey[j*4+3]=d.w;
      atomicAdd(&deg[d.x],1); atomicAdd(&deg[d.y],1);
      atomicAdd(&deg[d.z],1); atomicAdd(&deg[d.w],1);
      rr[j*4+0] = atomicAdd(&cnt[d.x>>BSH],1);
      rr[j*4+1] = atomicAdd(&cnt[d.y>>BSH],1);
      rr[j*4+2] = atomicAdd(&cnt[d.z>>BSH],1);
      rr[j*4+3] = atomicAdd(&cnt[d.w>>BSH],1);
    } else {
      rr[j*4+0]=rr[j*4+1]=rr[j*4+2]=rr[j*4+3] = -1;
    }
  }
  __syncthreads();
  if(t == 0){
    int run = 0;
    #pragma unroll
    for(int b=0;b<NBK;b++){ bst[b] = run; run += cnt[b]; }
  }
  __syncthreads();
  if(t < NBK) gbase[t] = atomicAdd(&bcur[t], cnt[t]);
  #pragma unroll
  for(int j=0;j<16;j++){
    if(rr[j] >= 0){
      int b = ey[j]>>BSH;
      stage[bst[b] + rr[j]] = make_int2(ex[j], ey[j]);
    }
  }
  __syncthreads();
  for(int k=t; k<nEdge; k+=256){
    int2 e = stage[k];
    int b = e.y>>BSH;
    int g = gbase[b] + (k - bst[b]);
    bsrc[g] = e.x;
    bdst[g] = (unsigned short)(e.y & ((1<<BSH)-1));
  }
}

// ---------- phase B: fine scatter from bucket-ordered edges ----------
// cursor atomics hit a sweeping ~16K-node window; csr writes sweep ~2MB
// windows -> both L2-resident, no write amplification.
__global__ __launch_bounds__(256) void k_fine(const int* __restrict__ bsrc,
                                              const unsigned short* __restrict__ bdst,
                                              const int* __restrict__ bbase,
                                              int* __restrict__ cursor,
                                              int* __restrict__ csr){
  __shared__ int sb[NBK+1];
  int t = threadIdx.x;
  if(t < NBK) sb[t] = bbase[t];
  if(t == 0)  sb[NBK] = NE;
  __syncthreads();
  int q  = blockIdx.x*256 + t;         // q < NE/4 (exact)
  int e0 = q*4;
  int4 s  = *(const int4*)(bsrc + e0);
  uint2 dd = *(const uint2*)(bdst + e0);
  int dl[4] = { (int)(dd.x & 0xffffu), (int)(dd.x >> 16),
                (int)(dd.y & 0xffffu), (int)(dd.y >> 16) };
  int sv[4] = { s.x, s.y, s.z, s.w };
  int b = 0;
  #pragma unroll
  for(int j=0;j<4;j++){
    int i = e0 + j;
    while(b < NBK-1 && sb[b+1] <= i) b++;
    int d = (b<<BSH) | dl[j];
    int p = atomicAdd(&cursor[d], 1);
    csr[p] = sv[j];
  }
}

// ---------- fallback: single-pass deg + 8-pass scatter (small ws) ----------
__global__ __launch_bounds__(256) void k_deg1(const int4* __restrict__ dst4,
                                              int* __restrict__ deg){
  int q = blockIdx.x*256 + threadIdx.x;
  int4 d = dst4[q];
  atomicAdd(&deg[d.x],1); atomicAdd(&deg[d.y],1);
  atomicAdd(&deg[d.z],1); atomicAdd(&deg[d.w],1);
}

__global__ __launch_bounds__(256) void k_scatter_pass(const int4* __restrict__ src4,
                                                      const int4* __restrict__ dst4,
                                                      int* __restrict__ cursor,
                                                      int* __restrict__ csr,
                                                      int lo, int hi){
  int t = blockIdx.x*256 + threadIdx.x;
  int4 d = dst4[t];
  bool bx = (d.x>=lo && d.x<hi);
  bool by = (d.y>=lo && d.y<hi);
  bool bz = (d.z>=lo && d.z<hi);
  bool bw = (d.w>=lo && d.w<hi);
  if(bx|by|bz|bw){
    int4 s = src4[t];
    if(bx){ int p = atomicAdd(&cursor[d.x], 1); csr[p] = s.x; }
    if(by){ int p = atomicAdd(&cursor[d.y], 1); csr[p] = s.y; }
    if(bz){ int p = atomicAdd(&cursor[d.z], 1); csr[p] = s.z; }
    if(bw){ int p = atomicAdd(&cursor[d.w], 1); csr[p] = s.w; }
  }
}

// ---------- 3-kernel exclusive scan of edge counts (deg-1), chunk=1024 ----------
__global__ void k_scan_part(const int* __restrict__ deg, int* __restrict__ part){
  __shared__ int sh[256];
  int b = blockIdx.x, t = threadIdx.x;
  int base = b*1024 + t*4;
  int s = 0;
  #pragma unroll
  for(int j=0;j<4;j++){ int i = base+j; if(i < NN) s += deg[i]-1; }
  sh[t] = s; __syncthreads();
  for(int o=128;o>0;o>>=1){ if(t<o) sh[t] += sh[t+o]; __syncthreads(); }
  if(t==0) part[b] = sh[0];
}

__global__ void k_scan_top(int* part, int nb){
  __shared__ int sh[256];
  int t = threadIdx.x;
  int v = (t<nb) ? part[t] : 0;
  sh[t] = v; __syncthreads();
  for(int o=1;o<256;o<<=1){
    int x = (t>=o) ? sh[t-o] : 0;
    __syncthreads();
    sh[t] += x;
    __syncthreads();
  }
  if(t<nb) part[t] = sh[t] - v;   // exclusive
}

__global__ void k_scan_fin(const int* __restrict__ deg, const int* __restrict__ part,
                           int* __restrict__ offs, int* __restrict__ cursor,
                           float* __restrict__ dinv){
  __shared__ int sh[256];
  int b = blockIdx.x, t = threadIdx.x;
  int base = b*1024 + t*4;
  int c[4]; int s = 0;
  #pragma unroll
  for(int j=0;j<4;j++){ int i = base+j; c[j] = (i < NN) ? deg[i]-1 : 0; s += c[j]; }
  sh[t] = s; __syncthreads();
  for(int o=1;o<256;o<<=1){
    int x = (t>=o) ? sh[t-o] : 0;
    __syncthreads();
    sh[t] += x;
    __syncthreads();
  }
  int run = sh[t] - s + part[b];
  #pragma unroll
  for(int j=0;j<4;j++){
    int i = base+j;
    if(i < NN){
      offs[i] = run; cursor[i] = run;
      dinv[i] = rsqrtf((float)(c[j]+1));
    }
    run += c[j];
  }
}

// ---------- h1b[row][c] = bf16( dinv[row] * (x @ W1)[row][c] ), 16 cols ----------
__global__ __launch_bounds__(256) void k_xw1(const float* __restrict__ x,
                                             const float* __restrict__ W1,
                                             const float* __restrict__ dinv,
                                             unsigned short* __restrict__ h1b){
  int row = blockIdx.x*256 + threadIdx.x;
  if(row >= NN) return;
  const float4* xr = (const float4*)(x + (size_t)row*FIN);
  float acc[16];
  #pragma unroll
  for(int c=0;c<16;c++) acc[c] = 0.f;
  #pragma unroll 5
  for(int kk=0;kk<25;kk++){
    float4 xv = xr[kk];
    const float* w = W1 + kk*4*16;   // uniform addresses -> scalar loads
    #pragma unroll
    for(int c=0;c<16;c++){
      acc[c] += xv.x*w[c] + xv.y*w[16+c] + xv.z*w[32+c] + xv.w*w[48+c];
    }
  }
  float dv = dinv[row];
  unsigned p[8];
  #pragma unroll
  for(int c=0;c<8;c++){
    p[c] = (unsigned)f2bf(acc[2*c]*dv) | ((unsigned)f2bf(acc[2*c+1]*dv) << 16);
  }
  uint4* o = (uint4*)(h1b + (size_t)row*16);
  o[0] = make_uint4(p[0],p[1],p[2],p[3]);
  o[1] = make_uint4(p[4],p[5],p[6],p[7]);
}

// ---------- layer-1 aggregation + bias + relu + @W2, fold dinv[d] into h2s ----------
// 16 lanes per node (lane = feature); bf16 h1 table (6.4MB -> better L2 hit)
__global__ __launch_bounds__(256) void k_agg1(const int* __restrict__ offs,
                                              const int* __restrict__ csr,
                                              const float* __restrict__ dinv,
                                              const unsigned short* __restrict__ h1b,
                                              const float* __restrict__ b1,
                                              const float* __restrict__ W2,
                                              float* __restrict__ h2s){
  int g = threadIdx.x >> 4;
  int f = threadIdx.x & 15;
  int d = blockIdx.x*16 + g;
  if(d >= NN) return;
  int begin = offs[d], end = offs[d+1];
  float dvd = dinv[d];
  float acc = bf2f(h1b[(size_t)d*16 + f]);     // self loop (dinv[d] folded)
  for(int base=begin; base<end; base+=16){
    int i = base + f;
    int sE = (i < end) ? csr[i] : 0;
    int cnt = end - base; if(cnt > 16) cnt = 16;
    for(int j=0;j<cnt;j++){
      int sj = __shfl(sE, j, 16);
      acc += bf2f(h1b[(size_t)sj*16 + f]);
    }
  }
  float out1 = dvd*acc + b1[f];
  float r = fmaxf(out1, 0.f);
  float p0 = r * W2[f*2+0];
  float p1 = r * W2[f*2+1];
  #pragma unroll
  for(int o=8;o>0;o>>=1){
    p0 += __shfl_xor(p0, o, 16);
    p1 += __shfl_xor(p1, o, 16);
  }
  if(f == 0){
    h2s[d*2+0] = dvd * p0;              // pre-fold dinv[d] for layer-2 gathers
    h2s[d*2+1] = dvd * p1;
  }
}

// ---------- layer-2 aggregation for sampled nodes only + log_softmax ----------
__global__ __launch_bounds__(256) void k_agg2(const int* __restrict__ offs,
                                              const int* __restrict__ csr,
                                              const float* __restrict__ dinv,
                                              const float* __restrict__ h2s,
                                              const float* __restrict__ b2,
                                              float* __restrict__ gout){
  int wid = threadIdx.x >> 6;
  int l   = threadIdx.x & 63;
  int idx = blockIdx.x*4 + wid;
  if(idx >= MR) return;
  int d = idx*20;
  int begin = offs[d], end = offs[d+1];
  float dvd = dinv[d];
  float a0 = 0.f, a1 = 0.f;
  for(int i=begin+l; i<end; i+=64){
    int s = csr[i];
    a0 += h2s[s*2+0];
    a1 += h2s[s*2+1];
  }
  if(l == 0){ a0 += h2s[d*2+0]; a1 += h2s[d*2+1]; }  // self loop
  #pragma unroll
  for(int o=32;o>0;o>>=1){
    a0 += __shfl_xor(a0, o, 64);
    a1 += __shfl_xor(a1, o, 64);
  }
  if(l == 0){
    float o0 = dvd*a0 + b2[0];
    float o1 = dvd*a1 + b2[1];
    float m = fmaxf(o0, o1);
    float lse = m + logf(expf(o0-m) + expf(o1-m));
    gout[idx*2+0] = o0 - lse;
    gout[idx*2+1] = o1 - lse;
  }
}

// ---------- global min/max over BP_input ([MR,5] = 3 inputs + gout) ----------
__global__ void k_minmax(const float* __restrict__ t1, const float* __restrict__ t2,
                         const float* __restrict__ t3, const float* __restrict__ g,
                         unsigned* mm){
  int tid = blockIdx.x*blockDim.x + threadIdx.x;
  float lo = 3.4e38f, hi = -3.4e38f;
  for(int i=tid; i<5*MR; i += blockDim.x*gridDim.x){
    float v;
    if(i < MR)        v = t1[i];
    else if(i < 2*MR) v = t2[i-MR];
    else if(i < 3*MR) v = t3[i-2*MR];
    else              v = g[i-3*MR];
    lo = fminf(lo, v); hi = fmaxf(hi, v);
  }
  #pragma unroll
  for(int o=32;o>0;o>>=1){
    lo = fminf(lo, __shfl_xor(lo, o, 64));
    hi = fmaxf(hi, __shfl_xor(hi, o, 64));
  }
  __shared__ float slo[4], shi[4];
  int w = threadIdx.x >> 6, l = threadIdx.x & 63;
  if(l == 0){ slo[w] = lo; shi[w] = hi; }
  __syncthreads();
  if(threadIdx.x == 0){
    for(int j=1;j<4;j++){ lo = fminf(lo, slo[j]); hi = fmaxf(hi, shi[j]); }
    atomicMin(&mm[0], enc_f(lo));
    atomicMax(&mm[1], enc_f(hi));
  }
}

// ---------- MLP head ----------
__global__ __launch_bounds__(256) void k_mlp(const float* __restrict__ t1, const float* __restrict__ t2,
                                             const float* __restrict__ t3, const float* __restrict__ g,
                                             const unsigned* __restrict__ mm,
                                             const float* __restrict__ W1, const float* __restrict__ b1,
                                             const float* __restrict__ W2, const float* __restrict__ b2,
                                             const float* __restrict__ W3, const float* __restrict__ b3,
                                             float* __restrict__ out){
  int i = blockIdx.x*256 + threadIdx.x;
  if(i >= MR) return;
  float mn = dec_f(mm[0]), mx = dec_f(mm[1]);
  float sc = 1.f/(mx - mn);
  float in[5];
  in[0] = (t1[i]   - mn)*sc;
  in[1] = (t2[i]   - mn)*sc;
  in[2] = (t3[i]   - mn)*sc;
  in[3] = (g[2*i]  - mn)*sc;
  in[4] = (g[2*i+1]- mn)*sc;
  float a[80];
  #pragma unroll
  for(int j=0;j<80;j++){
    float s = b1[j];
    #pragma unroll
    for(int k=0;k<5;k++) s += in[k]*W1[k*80+j];
    a[j] = fmaxf(s, 0.f);
  }
  float h[10];
  #pragma unroll
  for(int j=0;j<10;j++){
    float s = b2[j];
    #pragma unroll
    for(int k=0;k<80;k++) s += a[k]*W2[k*10+j];
    h[j] = fmaxf(s, 0.f);
  }
  float o = b3[0];
  #pragma unroll
  for(int k=0;k<10;k++) o += h[k]*W3[k];
  out[i] = 1.f/(1.f + expf(-o));
}

extern "C" void kernel_launch(void* const* d_in, const int* in_sizes, int n_in,
                              void* d_out, int out_size, void* d_ws, size_t ws_size,
                              hipStream_t stream) {
  (void)in_sizes; (void)n_in; (void)out_size;
  const int*   eidx    = (const int*)  d_in[0];   // [2, NE]
  const int*   src     = eidx;
  const int*   dst     = eidx + NE;
  const int4*  src4    = (const int4*) src;
  const int4*  dst4    = (const int4*) dst;
  const float* x       = (const float*)d_in[1];   // [NN, 100]
  const float* transE  = (const float*)d_in[4];
  const float* ComplEx = (const float*)d_in[5];
  const float* path    = (const float*)d_in[6];
  const float* ghW1    = (const float*)d_in[8];
  const float* ghb1    = (const float*)d_in[9];
  const float* ghW2    = (const float*)d_in[10];
  const float* ghb2    = (const float*)d_in[11];
  const float* mW1     = (const float*)d_in[16];
  const float* mb1     = (const float*)d_in[17];
  const float* mW2     = (const float*)d_in[18];
  const float* mb2     = (const float*)d_in[19];
  const float* mW3     = (const float*)d_in[20];
  const float* mb3     = (const float*)d_in[21];
  float* out = (float*)d_out;

  // workspace carve-up
  char* w = (char*)d_ws;
  size_t off = 0;
  auto alloc = [&](size_t bytes)->void*{
    void* p = w + off;
    off += (bytes + 255) & ~(size_t)255;
    return p;
  };
  int*      deg    = (int*)     alloc((size_t)NN*4);
  int*      offs   = (int*)     alloc((size_t)(NN+1)*4);
  int*      cursor = (int*)     alloc((size_t)NN*4);
  int*      csr    = (int*)     alloc((size_t)NE*4);
  float*    dinv   = (float*)   alloc((size_t)NN*4);
  unsigned short* h1b = (unsigned short*)alloc((size_t)NN*16*2);
  float*    h2s    = (float*)   alloc((size_t)NN*2*4);
  float*    gout   = (float*)   alloc((size_t)MR*2*4);
  unsigned* mm     = (unsigned*)alloc(256);
  int*      part   = (int*)     alloc(256*4);
  int*      bcnt   = (int*)     alloc(64*4);
  int*      bbase  = (int*)     alloc(64*4);
  int*      bcur   = (int*)     alloc(64*4);
  size_t common_end = off;
  int*            bsrc = (int*)           alloc((size_t)NE*4);
  unsigned short* bdst = (unsigned short*)alloc((size_t)NE*2);
  size_t need_main = off;
  bool use_bucket = (ws_size >= need_main);
  (void)common_end;

  const int EB4 = NE/4/256;            // 6250 (exact)
  const int BKB = (NE + EPB - 1)/EPB;  // 1563

  k_init<<<(NN+255)/256, 256, 0, stream>>>(deg, offs, mm, bcnt);
  if(use_bucket){
    k_bhist <<<EB4, 256, 0, stream>>>(dst4, bcnt);
    k_bscan <<<1, 64, 0, stream>>>(bcnt, bbase, bcur);
    k_bucket<<<BKB, 256, 0, stream>>>(src, dst, deg, bcur, bsrc, bdst);
  } else {
    k_deg1  <<<EB4, 256, 0, stream>>>(dst4, deg);
  }
  k_scan_part<<<SCAN_NB, 256, 0, stream>>>(deg, part);
  k_scan_top <<<1, 256, 0, stream>>>(part, SCAN_NB);
  k_scan_fin <<<SCAN_NB, 256, 0, stream>>>(deg, part, offs, cursor, dinv);
  if(use_bucket){
    k_fine  <<<EB4, 256, 0, stream>>>(bsrc, bdst, bbase, cursor, csr);
  } else {
    for(int p=0;p<NPASS;p++)
      k_scatter_pass<<<EB4, 256, 0, stream>>>(src4, dst4, cursor, csr,
                                              p*PRANGE, (p+1)*PRANGE);
  }
  k_xw1   <<<(NN+255)/256, 256, 0, stream>>>(x, ghW1, dinv, h1b);
  k_agg1  <<<NN/16, 256, 0, stream>>>(offs, csr, dinv, h1b, ghb1, ghW2, h2s);
  k_agg2  <<<(MR+3)/4, 256, 0, stream>>>(offs, csr, dinv, h2s, ghb2, gout);
  k_minmax<<<32, 256, 0, stream>>>(transE, ComplEx, path, gout, mm);
  k_mlp   <<<(MR+255)/256, 256, 0, stream>>>(transE, ComplEx, path, gout, mm,
                                             mW1, mb1, mW2, mb2, mW3, mb3, out);
}

// Round 4
// 1010.960 us; speedup vs baseline: 1.1965x; 1.1965x over previous
//
#include <hip/hip_runtime.h>
#include <math.h>

#define NN 200000      // nodes
#define NE 6400000     // edges
#define FIN 100        // input feature dim
#define MR 10000       // sampled rows (NN/20)
#define BSH 14         // coarse bucket shift (16384-node windows)
#define NBK 13         // ceil(NN / 16384)
#define NSB 1563       // ceil(NN / 128) sub-buckets of 128 nodes
#define EPB 4096       // edges per block in stage A/B

// ---------- float <-> monotonic-uint encoding for atomic min/max ----------
static __device__ __forceinline__ unsigned enc_f(float f){
  unsigned u = __float_as_uint(f);
  return (u & 0x80000000u) ? ~u : (u | 0x80000000u);
}
static __device__ __forceinline__ float dec_f(unsigned u){
  return (u & 0x80000000u) ? __uint_as_float(u ^ 0x80000000u) : __uint_as_float(~u);
}
// ---------- fp32 <-> bf16 (round-nearest-even) ----------
static __device__ __forceinline__ unsigned short f2bf(float f){
  unsigned u = __float_as_uint(f);
  return (unsigned short)((u + 0x7fffu + ((u >> 16) & 1u)) >> 16);
}
static __device__ __forceinline__ float bf2f(unsigned short h){
  return __uint_as_float(((unsigned)h) << 16);
}

// ---------- init: zero bcnt2 + gacc, minmax identity ----------
__global__ void k_init(int* bcnt2, float* gacc, unsigned* mm){
  int i = blockIdx.x*blockDim.x + threadIdx.x;
  if(i < NSB) bcnt2[i] = 0;
  if(i < 2*MR) gacc[i] = 0.f;
  if(i == 0){ mm[0] = 0xFFFFFFFFu; mm[1] = 0u; }
}

// ---------- sub-bucket histogram (dst>>7), LDS-staged ----------
__global__ __launch_bounds__(256) void k_hist(const int4* __restrict__ dst4,
                                              int* __restrict__ bcnt2){
  __shared__ int sh[NSB];
  for(int i=threadIdx.x;i<NSB;i+=256) sh[i]=0;
  __syncthreads();
  const int nq = NE/4;
  for(int q = blockIdx.x*256 + threadIdx.x; q < nq; q += gridDim.x*256){
    int4 d = dst4[q];
    atomicAdd(&sh[d.x>>7],1); atomicAdd(&sh[d.y>>7],1);
    atomicAdd(&sh[d.z>>7],1); atomicAdd(&sh[d.w>>7],1);
  }
  __syncthreads();
  for(int i=threadIdx.x;i<NSB;i+=256){ int v=sh[i]; if(v) atomicAdd(&bcnt2[i],v); }
}

// ---------- scan sub-bucket counts -> bases/cursors; derive bucket bases ----------
__global__ void k_scan2(const int* __restrict__ bcnt2, int* bbase2, int* bcur2,
                        int* bbase1, int* bcur1){
  __shared__ int part[256];
  int t = threadIdx.x;
  int base = t*7;
  int loc[7]; int s = 0;
  #pragma unroll
  for(int j=0;j<7;j++){ int i = base+j; loc[j] = (i<NSB)? bcnt2[i] : 0; s += loc[j]; }
  part[t] = s; __syncthreads();
  for(int o=1;o<256;o<<=1){
    int x = (t>=o)? part[t-o] : 0;
    __syncthreads();
    part[t] += x;
    __syncthreads();
  }
  int run = part[t] - s;          // exclusive prefix of this chunk
  #pragma unroll
  for(int j=0;j<7;j++){
    int i = base+j;
    if(i<NSB){ bbase2[i] = run; bcur2[i] = run; }
    run += loc[j];
  }
  if(t==0) bbase2[NSB] = NE;
  __syncthreads();                // orders global writes within block
  if(t < NBK){ int v = bbase2[t*128]; bbase1[t] = v; bcur1[t] = v; }
  if(t == NBK){ bbase1[NBK] = NE; }
}

// ---------- stage A: partition edges into 13 buckets, packed uint/edge ----------
// pack = (dst_local14 << 18) | src   (src < 2^18)
__global__ __launch_bounds__(256) void k_stageA(const int* __restrict__ src,
                                                const int* __restrict__ dst,
                                                int* __restrict__ bcur1,
                                                unsigned* __restrict__ bucket1){
  __shared__ unsigned stage[EPB];
  __shared__ unsigned char binOf[EPB];
  __shared__ int cnt[NBK], bst[NBK], gbase[NBK];
  int t = threadIdx.x;
  int ebase = blockIdx.x*EPB;
  int nEdge = min(EPB, NE - ebase);
  if(t < NBK) cnt[t] = 0;
  __syncthreads();
  unsigned pk[16]; int bb[16], rr[16];
  const int4* s4 = (const int4*)(src + ebase);
  const int4* d4 = (const int4*)(dst + ebase);
  #pragma unroll
  for(int j=0;j<4;j++){
    int q = t + j*256, eo = q*4;
    if(eo < nEdge){
      int4 s = s4[q]; int4 d = d4[q];
      int ds[4] = {d.x,d.y,d.z,d.w}, ss[4] = {s.x,s.y,s.z,s.w};
      #pragma unroll
      for(int k=0;k<4;k++){
        int b = ds[k]>>BSH;
        pk[j*4+k] = ((unsigned)(ds[k] & 16383) << 18) | (unsigned)ss[k];
        bb[j*4+k] = b;
        rr[j*4+k] = atomicAdd(&cnt[b], 1);
      }
    } else {
      rr[j*4+0]=rr[j*4+1]=rr[j*4+2]=rr[j*4+3] = -1;
    }
  }
  __syncthreads();
  if(t == 0){
    int run = 0;
    #pragma unroll
    for(int b=0;b<NBK;b++){ bst[b] = run; run += cnt[b]; }
  }
  __syncthreads();
  if(t < NBK && cnt[t]) gbase[t] = atomicAdd(&bcur1[t], cnt[t]);
  #pragma unroll
  for(int j=0;j<16;j++){
    if(rr[j] >= 0){
      int p = bst[bb[j]] + rr[j];
      stage[p] = pk[j]; binOf[p] = (unsigned char)bb[j];
    }
  }
  __syncthreads();
  for(int k=t; k<nEdge; k+=256){
    int b = binOf[k];
    bucket1[gbase[b] + (k - bst[b])] = stage[k];   // coalesced ~1.3KB runs
  }
}

// ---------- stage B: refine buckets into 1563 sub-buckets (128 nodes) ----------
// pack = (dst_local7 << 18) | src
__global__ __launch_bounds__(256) void k_stageB(const unsigned* __restrict__ bucket1,
                                                const int* __restrict__ bbase1,
                                                int* __restrict__ bcur2,
                                                unsigned* __restrict__ bucket2){
  __shared__ unsigned stage[EPB];
  __shared__ unsigned char binOf[EPB];
  __shared__ int cnt[256], bst[256], gbase[256];
  __shared__ int bb1[NBK+1];
  int t = threadIdx.x;
  int ebase = blockIdx.x*EPB;
  int nEdge = min(EPB, NE - ebase);
  if(t < NBK) bb1[t] = bbase1[t];
  if(t == NBK) bb1[NBK] = NE;
  cnt[t] = 0;
  __syncthreads();
  int bF = 0;
  while(bF < NBK-1 && bb1[bF+1] <= ebase) bF++;
  int sb0 = bF << 7;
  unsigned pk[16]; int ln[16], rr[16];
  const uint4* e4 = (const uint4*)(bucket1 + ebase);
  int b = bF;
  #pragma unroll
  for(int j=0;j<4;j++){
    int q = t + j*256, eo = q*4;
    if(eo < nEdge){
      uint4 e = e4[q];
      unsigned ev[4] = {e.x, e.y, e.z, e.w};
      #pragma unroll
      for(int k=0;k<4;k++){
        int gidx = ebase + eo + k;
        while(b < NBK-1 && bb1[b+1] <= gidx) b++;
        unsigned p = ev[k];
        unsigned dl14 = p >> 18;
        int sbl = ((b<<7) | (int)(dl14>>7)) - sb0;   // 0..255
        pk[j*4+k] = ((dl14 & 127u) << 18) | (p & 0x3FFFFu);
        ln[j*4+k] = sbl;
        rr[j*4+k] = atomicAdd(&cnt[sbl], 1);
      }
    } else {
      rr[j*4+0]=rr[j*4+1]=rr[j*4+2]=rr[j*4+3] = -1;
    }
  }
  __syncthreads();
  if(t == 0){
    int run = 0;
    for(int i=0;i<256;i++){ bst[i] = run; run += cnt[i]; }
  }
  __syncthreads();
  {
    int sbg = sb0 + t;
    if(cnt[t] && sbg < NSB) gbase[t] = atomicAdd(&bcur2[sbg], cnt[t]);
  }
  #pragma unroll
  for(int j=0;j<16;j++){
    if(rr[j] >= 0){
      int p = bst[ln[j]] + rr[j];
      stage[p] = pk[j]; binOf[p] = (unsigned char)ln[j];
    }
  }
  __syncthreads();
  for(int k=t; k<nEdge; k+=256){
    int bin = binOf[k];
    bucket2[gbase[bin] + (k - bst[bin])] = stage[k];   // coalesced ~128B runs
  }
}

// ---------- per-node degree from bucket2 (LDS counts) -> dinv ----------
__global__ __launch_bounds__(256) void k_cnt(const unsigned* __restrict__ bucket2,
                                             const int* __restrict__ bbase2,
                                             float* __restrict__ dinv){
  __shared__ int c[128];
  int sb = blockIdx.x, t = threadIdx.x;
  if(t < 128) c[t] = 0;
  __syncthreads();
  int e0 = bbase2[sb], e1 = bbase2[sb+1];
  for(int i=e0+t; i<e1; i+=256){
    unsigned pkv = bucket2[i];
    atomicAdd(&c[pkv>>18], 1);
  }
  __syncthreads();
  if(t < 128){
    int g = sb*128 + t;
    if(g < NN) dinv[g] = rsqrtf((float)(c[t] + 1));   // +1 self loop
  }
}

// ---------- h1b[row][c] = bf16( dinv[row] * (x @ W1)[row][c] ), 16 cols ----------
__global__ __launch_bounds__(256) void k_xw1(const float* __restrict__ x,
                                             const float* __restrict__ W1,
                                             const float* __restrict__ dinv,
                                             unsigned short* __restrict__ h1b){
  int row = blockIdx.x*256 + threadIdx.x;
  if(row >= NN) return;
  const float4* xr = (const float4*)(x + (size_t)row*FIN);
  float acc[16];
  #pragma unroll
  for(int c=0;c<16;c++) acc[c] = 0.f;
  #pragma unroll 5
  for(int kk=0;kk<25;kk++){
    float4 xv = xr[kk];
    const float* w = W1 + kk*4*16;   // uniform addresses -> scalar loads
    #pragma unroll
    for(int c=0;c<16;c++){
      acc[c] += xv.x*w[c] + xv.y*w[16+c] + xv.z*w[32+c] + xv.w*w[48+c];
    }
  }
  float dv = dinv[row];
  unsigned p[8];
  #pragma unroll
  for(int c=0;c<8;c++){
    p[c] = (unsigned)f2bf(acc[2*c]*dv) | ((unsigned)f2bf(acc[2*c+1]*dv) << 16);
  }
  uint4* o = (uint4*)(h1b + (size_t)row*16);
  o[0] = make_uint4(p[0],p[1],p[2],p[3]);
  o[1] = make_uint4(p[4],p[5],p[6],p[7]);
}

// ---------- fused layer-1 aggregation per sub-bucket + bias/relu/@W2 ----------
// one block per 128-node sub-bucket; LDS acc[128][16] via ds_add_f32.
__global__ __launch_bounds__(256) void k_aggfused(const unsigned* __restrict__ bucket2,
                                                  const int* __restrict__ bbase2,
                                                  const float* __restrict__ dinv,
                                                  const unsigned short* __restrict__ h1b,
                                                  const float* __restrict__ b1,
                                                  const float* __restrict__ W2,
                                                  float* __restrict__ h2s){
  __shared__ float acc[128*16];
  int t = threadIdx.x, sb = blockIdx.x;
  for(int i=t; i<2048; i+=256) acc[i] = 0.f;
  __syncthreads();
  int e0 = bbase2[sb], e1 = bbase2[sb+1];
  int grp = t>>4, f = t&15;
  for(int i=e0+grp; i<e1; i+=16){
    unsigned pkv = bucket2[i];           // 16 lanes same addr -> broadcast
    int srcn = (int)(pkv & 0x3FFFFu);
    int dl   = (int)(pkv >> 18);
    atomicAdd(&acc[dl*16 + f], bf2f(h1b[srcn*16 + f]));
  }
  __syncthreads();
  for(int n=grp; n<128; n+=16){
    int g = sb*128 + n;
    if(g < NN){
      float dvd = dinv[g];
      float val = acc[n*16 + f] + bf2f(h1b[g*16 + f]);   // + self loop
      float r = fmaxf(dvd*val + b1[f], 0.f);
      float p0 = r * W2[f*2+0];
      float p1 = r * W2[f*2+1];
      #pragma unroll
      for(int o=8;o>0;o>>=1){
        p0 += __shfl_xor(p0, o, 16);
        p1 += __shfl_xor(p1, o, 16);
      }
      if(f == 0){
        h2s[g*2+0] = dvd * p0;     // pre-fold dinv[d] for layer-2 gathers
        h2s[g*2+1] = dvd * p1;
      }
    }
  }
}

// ---------- layer-2: edge-parallel accumulation for sampled dst only ----------
__global__ __launch_bounds__(256) void k_agg2e(const unsigned* __restrict__ bucket2,
                                               const int* __restrict__ bbase2,
                                               const float* __restrict__ h2s,
                                               float* __restrict__ gacc){
  int sb = blockIdx.x, t = threadIdx.x;
  int e0 = bbase2[sb], e1 = bbase2[sb+1];
  int base = sb*128;
  for(int i=e0+t; i<e1; i+=256){
    unsigned pkv = bucket2[i];
    int g = base + (int)(pkv >> 18);
    if(g % 20 == 0){
      int srcn = (int)(pkv & 0x3FFFFu);
      int idx = g / 20;
      atomicAdd(&gacc[idx*2+0], h2s[srcn*2+0]);
      atomicAdd(&gacc[idx*2+1], h2s[srcn*2+1]);
    }
  }
}

// ---------- post: self loop + bias + log_softmax + fused minmax ----------
__global__ __launch_bounds__(256) void k_post(const float* __restrict__ gacc,
                                              const float* __restrict__ h2s,
                                              const float* __restrict__ dinv,
                                              const float* __restrict__ b2,
                                              const float* __restrict__ t1,
                                              const float* __restrict__ t2,
                                              const float* __restrict__ t3,
                                              float* __restrict__ gout,
                                              unsigned* __restrict__ mm){
  int i = blockIdx.x*256 + threadIdx.x;
  float lo = 3.4e38f, hi = -3.4e38f;
  if(i < MR){
    int g = i*20;
    float dvd = dinv[g];
    float o0 = dvd*(gacc[i*2+0] + h2s[g*2+0]) + b2[0];
    float o1 = dvd*(gacc[i*2+1] + h2s[g*2+1]) + b2[1];
    float m = fmaxf(o0, o1);
    float lse = m + logf(expf(o0-m) + expf(o1-m));
    float g0 = o0 - lse, g1 = o1 - lse;
    gout[i*2+0] = g0; gout[i*2+1] = g1;
    float a = t1[i], bb = t2[i], c = t3[i];
    lo = fminf(fminf(a,bb), fminf(c, fminf(g0,g1)));
    hi = fmaxf(fmaxf(a,bb), fmaxf(c, fmaxf(g0,g1)));
  }
  #pragma unroll
  for(int o=32;o>0;o>>=1){
    lo = fminf(lo, __shfl_xor(lo, o, 64));
    hi = fmaxf(hi, __shfl_xor(hi, o, 64));
  }
  __shared__ float slo[4], shi[4];
  int w = threadIdx.x >> 6, l = threadIdx.x & 63;
  if(l == 0){ slo[w] = lo; shi[w] = hi; }
  __syncthreads();
  if(threadIdx.x == 0){
    for(int j=1;j<4;j++){ lo = fminf(lo, slo[j]); hi = fmaxf(hi, shi[j]); }
    atomicMin(&mm[0], enc_f(lo));
    atomicMax(&mm[1], enc_f(hi));
  }
}

// ---------- MLP head ----------
__global__ __launch_bounds__(256) void k_mlp(const float* __restrict__ t1, const float* __restrict__ t2,
                                             const float* __restrict__ t3, const float* __restrict__ g,
                                             const unsigned* __restrict__ mm,
                                             const float* __restrict__ W1, const float* __restrict__ b1,
                                             const float* __restrict__ W2, const float* __restrict__ b2,
                                             const float* __restrict__ W3, const float* __restrict__ b3,
                                             float* __restrict__ out){
  int i = blockIdx.x*256 + threadIdx.x;
  if(i >= MR) return;
  float mn = dec_f(mm[0]), mx = dec_f(mm[1]);
  float sc = 1.f/(mx - mn);
  float in[5];
  in[0] = (t1[i]   - mn)*sc;
  in[1] = (t2[i]   - mn)*sc;
  in[2] = (t3[i]   - mn)*sc;
  in[3] = (g[2*i]  - mn)*sc;
  in[4] = (g[2*i+1]- mn)*sc;
  float a[80];
  #pragma unroll
  for(int j=0;j<80;j++){
    float s = b1[j];
    #pragma unroll
    for(int k=0;k<5;k++) s += in[k]*W1[k*80+j];
    a[j] = fmaxf(s, 0.f);
  }
  float h[10];
  #pragma unroll
  for(int j=0;j<10;j++){
    float s = b2[j];
    #pragma unroll
    for(int k=0;k<80;k++) s += a[k]*W2[k*10+j];
    h[j] = fmaxf(s, 0.f);
  }
  float o = b3[0];
  #pragma unroll
  for(int k=0;k<10;k++) o += h[k]*W3[k];
  out[i] = 1.f/(1.f + expf(-o));
}

extern "C" void kernel_launch(void* const* d_in, const int* in_sizes, int n_in,
                              void* d_out, int out_size, void* d_ws, size_t ws_size,
                              hipStream_t stream) {
  (void)in_sizes; (void)n_in; (void)out_size; (void)ws_size;
  const int*   eidx    = (const int*)  d_in[0];   // [2, NE]
  const int*   src     = eidx;
  const int*   dst     = eidx + NE;
  const int4*  dst4    = (const int4*) dst;
  const float* x       = (const float*)d_in[1];   // [NN, 100]
  const float* transE  = (const float*)d_in[4];
  const float* ComplEx = (const float*)d_in[5];
  const float* path    = (const float*)d_in[6];
  const float* ghW1    = (const float*)d_in[8];
  const float* ghb1    = (const float*)d_in[9];
  const float* ghW2    = (const float*)d_in[10];
  const float* ghb2    = (const float*)d_in[11];
  const float* mW1     = (const float*)d_in[16];
  const float* mb1     = (const float*)d_in[17];
  const float* mW2     = (const float*)d_in[18];
  const float* mb2     = (const float*)d_in[19];
  const float* mW3     = (const float*)d_in[20];
  const float* mb3     = (const float*)d_in[21];
  float* out = (float*)d_out;

  // workspace carve-up (~61 MB)
  char* w = (char*)d_ws;
  size_t off = 0;
  auto alloc = [&](size_t bytes)->void*{
    void* p = w + off;
    off += (bytes + 255) & ~(size_t)255;
    return p;
  };
  unsigned* bucket1 = (unsigned*)alloc((size_t)NE*4);
  unsigned* bucket2 = (unsigned*)alloc((size_t)NE*4);
  float*    dinv    = (float*)   alloc((size_t)NN*4);
  unsigned short* h1b = (unsigned short*)alloc((size_t)NN*16*2);
  float*    h2s     = (float*)   alloc((size_t)NN*2*4);
  float*    gacc    = (float*)   alloc((size_t)MR*2*4);
  float*    gout    = (float*)   alloc((size_t)MR*2*4);
  int*      bcnt2   = (int*)     alloc((size_t)(NSB+1)*4);
  int*      bbase2  = (int*)     alloc((size_t)(NSB+1)*4);
  int*      bcur2   = (int*)     alloc((size_t)(NSB+1)*4);
  int*      bbase1  = (int*)     alloc(64*4);
  int*      bcur1   = (int*)     alloc(64*4);
  unsigned* mm      = (unsigned*)alloc(256);

  const int SB_BLOCKS = (NE + EPB - 1)/EPB;   // 1563

  k_init    <<<(2*MR+255)/256, 256, 0, stream>>>(bcnt2, gacc, mm);
  k_hist    <<<1024, 256, 0, stream>>>(dst4, bcnt2);
  k_scan2   <<<1, 256, 0, stream>>>(bcnt2, bbase2, bcur2, bbase1, bcur1);
  k_stageA  <<<SB_BLOCKS, 256, 0, stream>>>(src, dst, bcur1, bucket1);
  k_stageB  <<<SB_BLOCKS, 256, 0, stream>>>(bucket1, bbase1, bcur2, bucket2);
  k_cnt     <<<NSB, 256, 0, stream>>>(bucket2, bbase2, dinv);
  k_xw1     <<<(NN+255)/256, 256, 0, stream>>>(x, ghW1, dinv, h1b);
  k_aggfused<<<NSB, 256, 0, stream>>>(bucket2, bbase2, dinv, h1b, ghb1, ghW2, h2s);
  k_agg2e   <<<NSB, 256, 0, stream>>>(bucket2, bbase2, h2s, gacc);
  k_post    <<<(MR+255)/256, 256, 0, stream>>>(gacc, h2s, dinv, ghb2,
                                               transE, ComplEx, path, gout, mm);
  k_mlp     <<<(MR+255)/256, 256, 0, stream>>>(transE, ComplEx, path, gout, mm,
                                               mW1, mb1, mW2, mb2, mW3, mb3, out);
}

// Round 5
// 458.482 us; speedup vs baseline: 2.6383x; 2.2050x over previous
//
#include <hip/hip_runtime.h>
#include <math.h>

#define NN 200000      // nodes
#define NE 6400000     // edges
#define FIN 100        // input feature dim
#define MR 10000       // sampled rows (NN/20)
#define BSH 14         // coarse bucket shift (16384-node windows)
#define NBK 13         // ceil(NN / 16384)
#define NSB 1563       // ceil(NN / 128) sub-buckets of 128 nodes
#define EPB 4096       // edges per block in stage A/B
#define STCAP 6144     // LDS sort capacity (mean 4096, sd~64 -> 32 sigma headroom)

// ---------- float <-> monotonic-uint encoding for atomic min/max ----------
static __device__ __forceinline__ unsigned enc_f(float f){
  unsigned u = __float_as_uint(f);
  return (u & 0x80000000u) ? ~u : (u | 0x80000000u);
}
static __device__ __forceinline__ float dec_f(unsigned u){
  return (u & 0x80000000u) ? __uint_as_float(u ^ 0x80000000u) : __uint_as_float(~u);
}
// ---------- fp32 <-> bf16 (round-nearest-even) ----------
static __device__ __forceinline__ unsigned short f2bf(float f){
  unsigned u = __float_as_uint(f);
  return (unsigned short)((u + 0x7fffu + ((u >> 16) & 1u)) >> 16);
}
static __device__ __forceinline__ float bf2f(unsigned short h){
  return __uint_as_float(((unsigned)h) << 16);
}

// ---------- init: zero bcnt2 + gacc, minmax identity ----------
__global__ void k_init(int* bcnt2, float* gacc, unsigned* mm){
  int i = blockIdx.x*blockDim.x + threadIdx.x;
  if(i < NSB) bcnt2[i] = 0;
  if(i < 2*MR) gacc[i] = 0.f;
  if(i == 0){ mm[0] = 0xFFFFFFFFu; mm[1] = 0u; }
}

// ---------- sub-bucket histogram (dst>>7), LDS-staged ----------
__global__ __launch_bounds__(256) void k_hist(const int4* __restrict__ dst4,
                                              int* __restrict__ bcnt2){
  __shared__ int sh[NSB];
  for(int i=threadIdx.x;i<NSB;i+=256) sh[i]=0;
  __syncthreads();
  const int nq = NE/4;
  for(int q = blockIdx.x*256 + threadIdx.x; q < nq; q += gridDim.x*256){
    int4 d = dst4[q];
    atomicAdd(&sh[d.x>>7],1); atomicAdd(&sh[d.y>>7],1);
    atomicAdd(&sh[d.z>>7],1); atomicAdd(&sh[d.w>>7],1);
  }
  __syncthreads();
  for(int i=threadIdx.x;i<NSB;i+=256){ int v=sh[i]; if(v) atomicAdd(&bcnt2[i],v); }
}

// ---------- scan sub-bucket counts -> bases/cursors; derive bucket bases ----------
__global__ void k_scan2(const int* __restrict__ bcnt2, int* bbase2, int* bcur2,
                        int* bbase1, int* bcur1){
  __shared__ int part[256];
  int t = threadIdx.x;
  int base = t*7;
  int loc[7]; int s = 0;
  #pragma unroll
  for(int j=0;j<7;j++){ int i = base+j; loc[j] = (i<NSB)? bcnt2[i] : 0; s += loc[j]; }
  part[t] = s; __syncthreads();
  for(int o=1;o<256;o<<=1){
    int x = (t>=o)? part[t-o] : 0;
    __syncthreads();
    part[t] += x;
    __syncthreads();
  }
  int run = part[t] - s;          // exclusive prefix of this chunk
  #pragma unroll
  for(int j=0;j<7;j++){
    int i = base+j;
    if(i<NSB){ bbase2[i] = run; bcur2[i] = run; }
    run += loc[j];
  }
  if(t==0) bbase2[NSB] = NE;
  __syncthreads();                // orders global writes within block
  if(t < NBK){ int v = bbase2[t*128]; bbase1[t] = v; bcur1[t] = v; }
  if(t == NBK){ bbase1[NBK] = NE; }
}

// ---------- stage A: partition edges into 13 buckets, packed uint/edge ----------
// pack = (dst_local14 << 18) | src   (src < 2^18)
__global__ __launch_bounds__(256) void k_stageA(const int* __restrict__ src,
                                                const int* __restrict__ dst,
                                                int* __restrict__ bcur1,
                                                unsigned* __restrict__ bucket1){
  __shared__ unsigned stage[EPB];
  __shared__ unsigned char binOf[EPB];
  __shared__ int cnt[NBK], bst[NBK], gbase[NBK];
  int t = threadIdx.x;
  int ebase = blockIdx.x*EPB;
  int nEdge = min(EPB, NE - ebase);
  if(t < NBK) cnt[t] = 0;
  __syncthreads();
  unsigned pk[16]; int bb[16], rr[16];
  const int4* s4 = (const int4*)(src + ebase);
  const int4* d4 = (const int4*)(dst + ebase);
  #pragma unroll
  for(int j=0;j<4;j++){
    int q = t + j*256, eo = q*4;
    if(eo < nEdge){
      int4 s = s4[q]; int4 d = d4[q];
      int ds[4] = {d.x,d.y,d.z,d.w}, ss[4] = {s.x,s.y,s.z,s.w};
      #pragma unroll
      for(int k=0;k<4;k++){
        int b = ds[k]>>BSH;
        pk[j*4+k] = ((unsigned)(ds[k] & 16383) << 18) | (unsigned)ss[k];
        bb[j*4+k] = b;
        rr[j*4+k] = atomicAdd(&cnt[b], 1);
      }
    } else {
      rr[j*4+0]=rr[j*4+1]=rr[j*4+2]=rr[j*4+3] = -1;
    }
  }
  __syncthreads();
  if(t == 0){
    int run = 0;
    #pragma unroll
    for(int b=0;b<NBK;b++){ bst[b] = run; run += cnt[b]; }
  }
  __syncthreads();
  if(t < NBK && cnt[t]) gbase[t] = atomicAdd(&bcur1[t], cnt[t]);
  #pragma unroll
  for(int j=0;j<16;j++){
    if(rr[j] >= 0){
      int p = bst[bb[j]] + rr[j];
      stage[p] = pk[j]; binOf[p] = (unsigned char)bb[j];
    }
  }
  __syncthreads();
  for(int k=t; k<nEdge; k+=256){
    int b = binOf[k];
    bucket1[gbase[b] + (k - bst[b])] = stage[k];   // coalesced ~1.3KB runs
  }
}

// ---------- stage B: refine buckets into 1563 sub-buckets (128 nodes) ----------
// pack = (dst_local7 << 18) | src
__global__ __launch_bounds__(256) void k_stageB(const unsigned* __restrict__ bucket1,
                                                const int* __restrict__ bbase1,
                                                int* __restrict__ bcur2,
                                                unsigned* __restrict__ bucket2){
  __shared__ unsigned stage[EPB];
  __shared__ unsigned char binOf[EPB];
  __shared__ int cnt[256], bst[256], gbase[256];
  __shared__ int bb1[NBK+1];
  int t = threadIdx.x;
  int ebase = blockIdx.x*EPB;
  int nEdge = min(EPB, NE - ebase);
  if(t < NBK) bb1[t] = bbase1[t];
  if(t == NBK) bb1[NBK] = NE;
  cnt[t] = 0;
  __syncthreads();
  int bF = 0;
  while(bF < NBK-1 && bb1[bF+1] <= ebase) bF++;
  int sb0 = bF << 7;
  unsigned pk[16]; int ln[16], rr[16];
  const uint4* e4 = (const uint4*)(bucket1 + ebase);
  int b = bF;
  #pragma unroll
  for(int j=0;j<4;j++){
    int q = t + j*256, eo = q*4;
    if(eo < nEdge){
      uint4 e = e4[q];
      unsigned ev[4] = {e.x, e.y, e.z, e.w};
      #pragma unroll
      for(int k=0;k<4;k++){
        int gidx = ebase + eo + k;
        while(b < NBK-1 && bb1[b+1] <= gidx) b++;
        unsigned p = ev[k];
        unsigned dl14 = p >> 18;
        int sbl = ((b<<7) | (int)(dl14>>7)) - sb0;   // 0..255
        pk[j*4+k] = ((dl14 & 127u) << 18) | (p & 0x3FFFFu);
        ln[j*4+k] = sbl;
        rr[j*4+k] = atomicAdd(&cnt[sbl], 1);
      }
    } else {
      rr[j*4+0]=rr[j*4+1]=rr[j*4+2]=rr[j*4+3] = -1;
    }
  }
  __syncthreads();
  if(t == 0){
    int run = 0;
    for(int i=0;i<256;i++){ bst[i] = run; run += cnt[i]; }
  }
  __syncthreads();
  {
    int sbg = sb0 + t;
    if(cnt[t] && sbg < NSB) gbase[t] = atomicAdd(&bcur2[sbg], cnt[t]);
  }
  #pragma unroll
  for(int j=0;j<16;j++){
    if(rr[j] >= 0){
      int p = bst[ln[j]] + rr[j];
      stage[p] = pk[j]; binOf[p] = (unsigned char)ln[j];
    }
  }
  __syncthreads();
  for(int k=t; k<nEdge; k+=256){
    int bin = binOf[k];
    bucket2[gbase[bin] + (k - bst[bin])] = stage[k];   // coalesced ~128B runs
  }
}

// ---------- per-node degree from bucket2 (LDS counts) -> dinv ----------
__global__ __launch_bounds__(256) void k_cnt(const unsigned* __restrict__ bucket2,
                                             const int* __restrict__ bbase2,
                                             float* __restrict__ dinv){
  __shared__ int c[128];
  int sb = blockIdx.x, t = threadIdx.x;
  if(t < 128) c[t] = 0;
  __syncthreads();
  int e0 = bbase2[sb], e1 = bbase2[sb+1];
  for(int i=e0+t; i<e1; i+=256){
    unsigned pkv = bucket2[i];
    atomicAdd(&c[pkv>>18], 1);
  }
  __syncthreads();
  if(t < 128){
    int g = sb*128 + t;
    if(g < NN) dinv[g] = rsqrtf((float)(c[t] + 1));   // +1 self loop
  }
}

// ---------- h1b[row][c] = bf16( dinv[row] * (x @ W1)[row][c] ), 16 cols ----------
__global__ __launch_bounds__(256) void k_xw1(const float* __restrict__ x,
                                             const float* __restrict__ W1,
                                             const float* __restrict__ dinv,
                                             unsigned short* __restrict__ h1b){
  int row = blockIdx.x*256 + threadIdx.x;
  if(row >= NN) return;
  const float4* xr = (const float4*)(x + (size_t)row*FIN);
  float acc[16];
  #pragma unroll
  for(int c=0;c<16;c++) acc[c] = 0.f;
  #pragma unroll 5
  for(int kk=0;kk<25;kk++){
    float4 xv = xr[kk];
    const float* w = W1 + kk*4*16;   // uniform addresses -> scalar loads
    #pragma unroll
    for(int c=0;c<16;c++){
      acc[c] += xv.x*w[c] + xv.y*w[16+c] + xv.z*w[32+c] + xv.w*w[48+c];
    }
  }
  float dv = dinv[row];
  unsigned p[8];
  #pragma unroll
  for(int c=0;c<8;c++){
    p[c] = (unsigned)f2bf(acc[2*c]*dv) | ((unsigned)f2bf(acc[2*c+1]*dv) << 16);
  }
  uint4* o = (uint4*)(h1b + (size_t)row*16);
  o[0] = make_uint4(p[0],p[1],p[2],p[3]);
  o[1] = make_uint4(p[4],p[5],p[6],p[7]);
}

// ---------- fused layer-1 aggregation per sub-bucket + bias/relu/@W2 ----------
// In-block counting sort to node granularity (LDS), then per-node REGISTER
// accumulation with 4 independent gathers in flight (k_agg1's MLP pattern,
// no LDS atomics, no dependent-load chain). 512 threads = 8 waves.
__global__ __launch_bounds__(512) void k_aggfused(const unsigned* __restrict__ bucket2,
                                                  const int* __restrict__ bbase2,
                                                  const float* __restrict__ dinv,
                                                  const unsigned short* __restrict__ h1b,
                                                  const float* __restrict__ b1,
                                                  const float* __restrict__ W2,
                                                  float* __restrict__ h2s){
  __shared__ unsigned srt[STCAP];          // sorted src ids (24 KB)
  __shared__ int cnt[128], coff[129], cur[128];
  __shared__ int wsum0;
  int t = threadIdx.x, sb = blockIdx.x;
  int e0 = bbase2[sb], e1 = bbase2[sb+1];
  int n  = e1 - e0;
  bool ok = (n <= STCAP);                  // block-uniform
  int grp = t>>4, f = t&15;                // 32 groups of 16 lanes
  if(t < 128) cnt[t] = 0;
  __syncthreads();

  if(ok){
    // pass 1: per-node histogram
    for(int i=e0+t; i<e1; i+=512) atomicAdd(&cnt[bucket2[i]>>18], 1);
    __syncthreads();
    // scan 128 bins: wave-level shfl scan (two waves' worth of lanes)
    int v = (t<128) ? cnt[t] : 0;
    int s = v;
    #pragma unroll
    for(int o=1;o<64;o<<=1){
      int u = __shfl_up(s, o, 64);
      if((t&63) >= o) s += u;
    }
    if(t == 63) wsum0 = s;
    __syncthreads();
    if(t < 128){
      int ex = s - v + ((t>=64) ? wsum0 : 0);
      coff[t] = ex; cur[t] = ex;
    }
    if(t == 0) coff[128] = n;
    __syncthreads();
    // pass 2: scatter into LDS (bucket2 is L2-hot from pass 1)
    for(int i=e0+t; i<e1; i+=512){
      unsigned pkv = bucket2[i];
      int p = atomicAdd(&cur[pkv>>18], 1);
      srt[p] = pkv & 0x3FFFFu;
    }
    __syncthreads();
    // per-node register accumulation, 4 gathers in flight
    for(int nd=grp; nd<128; nd+=32){
      int g = sb*128 + nd;
      if(g >= NN) continue;
      int s0 = coff[nd], s1 = coff[nd+1];
      float acc = bf2f(h1b[(size_t)g*16 + f]);     // self loop
      int j = s0;
      for(; j+4 <= s1; j+=4){
        unsigned a0=srt[j], a1=srt[j+1], a2=srt[j+2], a3=srt[j+3];
        float x0 = bf2f(h1b[a0*16 + f]);
        float x1 = bf2f(h1b[a1*16 + f]);
        float x2 = bf2f(h1b[a2*16 + f]);
        float x3 = bf2f(h1b[a3*16 + f]);
        acc += (x0+x1) + (x2+x3);
      }
      for(; j<s1; j++) acc += bf2f(h1b[srt[j]*16 + f]);
      float dvd = dinv[g];
      float r = fmaxf(dvd*acc + b1[f], 0.f);
      float p0 = r * W2[f*2+0];
      float p1 = r * W2[f*2+1];
      #pragma unroll
      for(int o=8;o>0;o>>=1){
        p0 += __shfl_xor(p0, o, 16);
        p1 += __shfl_xor(p1, o, 16);
      }
      if(f == 0){
        h2s[g*2+0] = dvd * p0;     // pre-fold dinv[d] for layer-2 gathers
        h2s[g*2+1] = dvd * p1;
      }
    }
  } else {
    // fallback (n > STCAP, ~impossible with uniform dst): LDS-atomic path
    float* accf = (float*)srt;               // reuse srt as acc[128][16]
    for(int i=t; i<2048; i+=512) accf[i] = 0.f;
    __syncthreads();
    for(int i=e0+grp; i<e1; i+=32){
      unsigned pkv = bucket2[i];
      atomicAdd(&accf[(pkv>>18)*16 + f], bf2f(h1b[(pkv & 0x3FFFFu)*16 + f]));
    }
    __syncthreads();
    for(int nd=grp; nd<128; nd+=32){
      int g = sb*128 + nd;
      if(g >= NN) continue;
      float dvd = dinv[g];
      float acc = accf[nd*16 + f] + bf2f(h1b[(size_t)g*16 + f]);
      float r = fmaxf(dvd*acc + b1[f], 0.f);
      float p0 = r * W2[f*2+0];
      float p1 = r * W2[f*2+1];
      #pragma unroll
      for(int o=8;o>0;o>>=1){
        p0 += __shfl_xor(p0, o, 16);
        p1 += __shfl_xor(p1, o, 16);
      }
      if(f == 0){
        h2s[g*2+0] = dvd * p0;
        h2s[g*2+1] = dvd * p1;
      }
    }
  }
}

// ---------- layer-2: edge-parallel accumulation for sampled dst only ----------
__global__ __launch_bounds__(256) void k_agg2e(const unsigned* __restrict__ bucket2,
                                               const int* __restrict__ bbase2,
                                               const float* __restrict__ h2s,
                                               float* __restrict__ gacc){
  int sb = blockIdx.x, t = threadIdx.x;
  int e0 = bbase2[sb], e1 = bbase2[sb+1];
  int base = sb*128;
  for(int i=e0+t; i<e1; i+=256){
    unsigned pkv = bucket2[i];
    int g = base + (int)(pkv >> 18);
    if(g % 20 == 0){
      int srcn = (int)(pkv & 0x3FFFFu);
      int idx = g / 20;
      atomicAdd(&gacc[idx*2+0], h2s[srcn*2+0]);
      atomicAdd(&gacc[idx*2+1], h2s[srcn*2+1]);
    }
  }
}

// ---------- post: self loop + bias + log_softmax + fused minmax ----------
__global__ __launch_bounds__(256) void k_post(const float* __restrict__ gacc,
                                              const float* __restrict__ h2s,
                                              const float* __restrict__ dinv,
                                              const float* __restrict__ b2,
                                              const float* __restrict__ t1,
                                              const float* __restrict__ t2,
                                              const float* __restrict__ t3,
                                              float* __restrict__ gout,
                                              unsigned* __restrict__ mm){
  int i = blockIdx.x*256 + threadIdx.x;
  float lo = 3.4e38f, hi = -3.4e38f;
  if(i < MR){
    int g = i*20;
    float dvd = dinv[g];
    float o0 = dvd*(gacc[i*2+0] + h2s[g*2+0]) + b2[0];
    float o1 = dvd*(gacc[i*2+1] + h2s[g*2+1]) + b2[1];
    float m = fmaxf(o0, o1);
    float lse = m + logf(expf(o0-m) + expf(o1-m));
    float g0 = o0 - lse, g1 = o1 - lse;
    gout[i*2+0] = g0; gout[i*2+1] = g1;
    float a = t1[i], bb = t2[i], c = t3[i];
    lo = fminf(fminf(a,bb), fminf(c, fminf(g0,g1)));
    hi = fmaxf(fmaxf(a,bb), fmaxf(c, fmaxf(g0,g1)));
  }
  #pragma unroll
  for(int o=32;o>0;o>>=1){
    lo = fminf(lo, __shfl_xor(lo, o, 64));
    hi = fmaxf(hi, __shfl_xor(hi, o, 64));
  }
  __shared__ float slo[4], shi[4];
  int w = threadIdx.x >> 6, l = threadIdx.x & 63;
  if(l == 0){ slo[w] = lo; shi[w] = hi; }
  __syncthreads();
  if(threadIdx.x == 0){
    for(int j=1;j<4;j++){ lo = fminf(lo, slo[j]); hi = fmaxf(hi, shi[j]); }
    atomicMin(&mm[0], enc_f(lo));
    atomicMax(&mm[1], enc_f(hi));
  }
}

// ---------- MLP head ----------
__global__ __launch_bounds__(256) void k_mlp(const float* __restrict__ t1, const float* __restrict__ t2,
                                             const float* __restrict__ t3, const float* __restrict__ g,
                                             const unsigned* __restrict__ mm,
                                             const float* __restrict__ W1, const float* __restrict__ b1,
                                             const float* __restrict__ W2, const float* __restrict__ b2,
                                             const float* __restrict__ W3, const float* __restrict__ b3,
                                             float* __restrict__ out){
  int i = blockIdx.x*256 + threadIdx.x;
  if(i >= MR) return;
  float mn = dec_f(mm[0]), mx = dec_f(mm[1]);
  float sc = 1.f/(mx - mn);
  float in[5];
  in[0] = (t1[i]   - mn)*sc;
  in[1] = (t2[i]   - mn)*sc;
  in[2] = (t3[i]   - mn)*sc;
  in[3] = (g[2*i]  - mn)*sc;
  in[4] = (g[2*i+1]- mn)*sc;
  float a[80];
  #pragma unroll
  for(int j=0;j<80;j++){
    float s = b1[j];
    #pragma unroll
    for(int k=0;k<5;k++) s += in[k]*W1[k*80+j];
    a[j] = fmaxf(s, 0.f);
  }
  float h[10];
  #pragma unroll
  for(int j=0;j<10;j++){
    float s = b2[j];
    #pragma unroll
    for(int k=0;k<80;k++) s += a[k]*W2[k*10+j];
    h[j] = fmaxf(s, 0.f);
  }
  float o = b3[0];
  #pragma unroll
  for(int k=0;k<10;k++) o += h[k]*W3[k];
  out[i] = 1.f/(1.f + expf(-o));
}

extern "C" void kernel_launch(void* const* d_in, const int* in_sizes, int n_in,
                              void* d_out, int out_size, void* d_ws, size_t ws_size,
                              hipStream_t stream) {
  (void)in_sizes; (void)n_in; (void)out_size; (void)ws_size;
  const int*   eidx    = (const int*)  d_in[0];   // [2, NE]
  const int*   src     = eidx;
  const int*   dst     = eidx + NE;
  const int4*  dst4    = (const int4*) dst;
  const float* x       = (const float*)d_in[1];   // [NN, 100]
  const float* transE  = (const float*)d_in[4];
  const float* ComplEx = (const float*)d_in[5];
  const float* path    = (const float*)d_in[6];
  const float* ghW1    = (const float*)d_in[8];
  const float* ghb1    = (const float*)d_in[9];
  const float* ghW2    = (const float*)d_in[10];
  const float* ghb2    = (const float*)d_in[11];
  const float* mW1     = (const float*)d_in[16];
  const float* mb1     = (const float*)d_in[17];
  const float* mW2     = (const float*)d_in[18];
  const float* mb2     = (const float*)d_in[19];
  const float* mW3     = (const float*)d_in[20];
  const float* mb3     = (const float*)d_in[21];
  float* out = (float*)d_out;

  // workspace carve-up (~61 MB)
  char* w = (char*)d_ws;
  size_t off = 0;
  auto alloc = [&](size_t bytes)->void*{
    void* p = w + off;
    off += (bytes + 255) & ~(size_t)255;
    return p;
  };
  unsigned* bucket1 = (unsigned*)alloc((size_t)NE*4);
  unsigned* bucket2 = (unsigned*)alloc((size_t)NE*4);
  float*    dinv    = (float*)   alloc((size_t)NN*4);
  unsigned short* h1b = (unsigned short*)alloc((size_t)NN*16*2);
  float*    h2s     = (float*)   alloc((size_t)NN*2*4);
  float*    gacc    = (float*)   alloc((size_t)MR*2*4);
  float*    gout    = (float*)   alloc((size_t)MR*2*4);
  int*      bcnt2   = (int*)     alloc((size_t)(NSB+1)*4);
  int*      bbase2  = (int*)     alloc((size_t)(NSB+1)*4);
  int*      bcur2   = (int*)     alloc((size_t)(NSB+1)*4);
  int*      bbase1  = (int*)     alloc(64*4);
  int*      bcur1   = (int*)     alloc(64*4);
  unsigned* mm      = (unsigned*)alloc(256);

  const int SB_BLOCKS = (NE + EPB - 1)/EPB;   // 1563

  k_init    <<<(2*MR+255)/256, 256, 0, stream>>>(bcnt2, gacc, mm);
  k_hist    <<<1024, 256, 0, stream>>>(dst4, bcnt2);
  k_scan2   <<<1, 256, 0, stream>>>(bcnt2, bbase2, bcur2, bbase1, bcur1);
  k_stageA  <<<SB_BLOCKS, 256, 0, stream>>>(src, dst, bcur1, bucket1);
  k_stageB  <<<SB_BLOCKS, 256, 0, stream>>>(bucket1, bbase1, bcur2, bucket2);
  k_cnt     <<<NSB, 256, 0, stream>>>(bucket2, bbase2, dinv);
  k_xw1     <<<(NN+255)/256, 256, 0, stream>>>(x, ghW1, dinv, h1b);
  k_aggfused<<<NSB, 512, 0, stream>>>(bucket2, bbase2, dinv, h1b, ghb1, ghW2, h2s);
  k_agg2e   <<<NSB, 256, 0, stream>>>(bucket2, bbase2, h2s, gacc);
  k_post    <<<(MR+255)/256, 256, 0, stream>>>(gacc, h2s, dinv, ghb2,
                                               transE, ComplEx, path, gout, mm);
  k_mlp     <<<(MR+255)/256, 256, 0, stream>>>(transE, ComplEx, path, gout, mm,
                                               mW1, mb1, mW2, mb2, mW3, mb3, out);
}